// Round 4
// baseline (168.772 us; speedup 1.0000x reference)
//
#include <hip/hip_runtime.h>
#include <stdint.h>

// Problem constants (B=16, A=3, H=W=76, ATTR=5+80=85)
// Input:  fp32, shape (16, 255, 76, 76)   = 23,566,080 floats (94.3 MB)
// Output: fp32, shape (16, 3, 76, 76, 85) = 23,566,080 floats (94.3 MB)
#define NB      16
#define NA      3
#define HH_     76
#define WW_     76
#define S_TOT   (HH_ * WW_)          // 5776 spatial positions
#define ATTR    85
#define TILE_S  76                   // spatial positions per block
#define TILES   (S_TOT / TILE_S)     // 76
#define CHUNKS4 (TILE_S / 4)         // 19 float4 chunks per attrib row
#define UNITS_L (ATTR * CHUNKS4)     // 1615 load units per tile
#define UNITS_S (TILE_S * ATTR / 4)  // 1615 float4 store units per tile
#define NTHREADS 256
#define LOG2E   1.44269504088896340f

typedef __attribute__((ext_vector_type(4))) float float4v;

__device__ __forceinline__ float fast_sigmoid(float x) {
    // 1 / (1 + e^-x) = rcp(1 + exp2(-x*log2e)); x ~ N(0,1), |x| <= ~6, finite
    float e = __builtin_amdgcn_exp2f(x * (-LOG2E));
    return __builtin_amdgcn_rcpf(1.0f + e);
}

__global__ __launch_bounds__(NTHREADS)
void yolo_layer_kernel(const float* __restrict__ in,
                       float* __restrict__ out) {
    // LDS holds the fp32 output tile verbatim: [TILE_S][ATTR], unpadded.
    // Store phase is then a pure contiguous b128 copy.
    __shared__ __attribute__((aligned(16))) float lds[TILE_S * ATTR]; // 25840 B -> 6 blocks/CU

    const int tid  = threadIdx.x;
    const int tile = blockIdx.x;          // 0..75  (spatial tile)
    const int BA   = blockIdx.y;          // 0..47  (b*3 + a)
    const int a    = BA % NA;
    const int s0   = tile * TILE_S;

    // anchor constants (faithful to reference's off-by-one anchor_h indexing:
    // ANCHOR_W = [10,13,16], ANCHOR_H = [13,16,30])
    const float aw = (a == 0) ? 10.0f : (a == 1) ? 13.0f : 16.0f;
    const float ah = (a == 0) ? 13.0f : (a == 1) ? 16.0f : 30.0f;
    const float cw = aw * (1.0f / 608.0f);
    const float ch = ah * (1.0f / 608.0f);

    // x[b, a*85+k, h, w] flat = (BA*85 + k)*5776 + s ; all float4 bases 16B-aligned:
    // BA*485860, k*5776, s0=tile*76, sl=c*4 are all multiples of 4 elements.
    const float* inb = in + (size_t)BA * (ATTR * S_TOT) + s0;

    // ---------- Phase 1: coalesced float4 load + math + LDS transpose-scatter ----------
    for (int u = tid; u < UNITS_L; u += NTHREADS) {
        const int k  = u / CHUNKS4;           // attrib row, fixed per lane per unit
        const int c  = u - k * CHUNKS4;
        const int sl = c * 4;                 // local spatial start of this float4

        const float4v v = *(const float4v*)(inb + (size_t)k * S_TOT + sl);
        float r[4];

        if (k >= 4) {
            // conf + class scores: plain sigmoid (~95% of elements, convergent)
            #pragma unroll
            for (int j = 0; j < 4; ++j) {
                r[j] = fast_sigmoid(v[j]);
            }
        } else {
            // bx/by/bw/bh rows — only units u < 76 ever land here
            #pragma unroll
            for (int j = 0; j < 4; ++j) {
                float x  = v[j];
                int   sp = s0 + sl + j;           // global spatial index = h*76 + w
                int   hy = sp / WW_;
                int   wx = sp - hy * WW_;
                if      (k == 0) r[j] = ((float)wx + fast_sigmoid(x)) * (1.0f / 76.0f);
                else if (k == 1) r[j] = ((float)hy + fast_sigmoid(x)) * (1.0f / 76.0f);
                else if (k == 2) r[j] = __builtin_amdgcn_exp2f(x * LOG2E) * cw;
                else             r[j] = __builtin_amdgcn_exp2f(x * LOG2E) * ch;
            }
        }

        // scatter into output-ordered LDS: elem (sl+j)*85 + k
        float* lp = &lds[sl * ATTR + k];
        #pragma unroll
        for (int j = 0; j < 4; ++j) {
            lp[j * ATTR] = r[j];
        }
    }

    __syncthreads();

    // ---------- Phase 2: contiguous LDS -> global, 16B vectors ----------
    // out tile base elem = (BA*5776 + s0)*85 ; (BA*5776 + s0) % 4 == 0 -> 16B aligned
    float4v* outv = (float4v*)(out + ((size_t)BA * S_TOT + s0) * ATTR);
    const float4v* ldsv = (const float4v*)lds;
    for (int u = tid; u < UNITS_S; u += NTHREADS) {
        outv[u] = ldsv[u];
    }
}

extern "C" void kernel_launch(void* const* d_in, const int* in_sizes, int n_in,
                              void* d_out, int out_size, void* d_ws, size_t ws_size,
                              hipStream_t stream) {
    const float* in = (const float*)d_in[0];   // fp32 input
    float* out = (float*)d_out;                // fp32 output

    dim3 grid(TILES, NB * NA);   // (76, 48) = 3648 blocks
    dim3 block(NTHREADS);
    yolo_layer_kernel<<<grid, block, 0, stream>>>(in, out);
}

// Round 5
// 165.122 us; speedup vs baseline: 1.0221x; 1.0221x over previous
//
#include <hip/hip_runtime.h>
#include <stdint.h>

// Problem constants (B=16, A=3, H=W=76, ATTR=5+80=85)
// Input:  fp32, shape (16, 255, 76, 76)   = 23,566,080 floats (94.3 MB)
// Output: fp32, shape (16, 3, 76, 76, 85) = 23,566,080 floats (94.3 MB)
#define NB      16
#define NA      3
#define HH_     76
#define WW_     76
#define S_TOT   (HH_ * WW_)          // 5776 spatial positions
#define ATTR    85
#define TILE_S  76                   // spatial positions per block
#define TILES   (S_TOT / TILE_S)     // 76
#define CHUNKS4 (TILE_S / 4)         // 19 float4 chunks per attrib row
#define UNITS   (ATTR * CHUNKS4)     // 1615 float4 units per tile (load AND store)
#define NTHREADS 256
#define NBATCH  7                    // ceil(UNITS / NTHREADS)
#define LOG2E   1.44269504088896340f

typedef __attribute__((ext_vector_type(4))) float float4v;

__device__ __forceinline__ float fast_sigmoid(float x) {
    // 1 / (1 + e^-x) = rcp(1 + exp2(-x*log2e)); x ~ N(0,1), |x| <= ~6, finite
    float e = __builtin_amdgcn_exp2f(x * (-LOG2E));
    return __builtin_amdgcn_rcpf(1.0f + e);
}

__global__ __launch_bounds__(NTHREADS)
void yolo_layer_kernel(const float* __restrict__ in,
                       float* __restrict__ out) {
    // LDS holds the fp32 output tile verbatim: [TILE_S][ATTR], unpadded.
    __shared__ __attribute__((aligned(16))) float lds[TILE_S * ATTR]; // 25840 B -> 6 blocks/CU

    const int tid  = threadIdx.x;
    const int tile = blockIdx.x;          // 0..75  (spatial tile)
    const int BA   = blockIdx.y;          // 0..47  (b*3 + a)
    const int a    = BA % NA;
    const int s0   = tile * TILE_S;

    // anchor constants (faithful to reference's off-by-one anchor_h indexing:
    // ANCHOR_W = [10,13,16], ANCHOR_H = [13,16,30])
    const float aw = (a == 0) ? 10.0f : (a == 1) ? 13.0f : 16.0f;
    const float ah = (a == 0) ? 13.0f : (a == 1) ? 16.0f : 30.0f;
    const float cw = aw * (1.0f / 608.0f);
    const float ch = ah * (1.0f / 608.0f);

    const float* inb = in + (size_t)BA * (ATTR * S_TOT) + s0;

    // ---------- Phase 1a: issue ALL per-thread loads back-to-back (7x MLP) ----------
    // Latency fix for R4's 59us @ 43% BW: the old loop held 1 outstanding load/thread
    // (load -> waitcnt -> math -> ds_write). Batch the 7 loads before any consumer.
    float4v v[NBATCH];
    #pragma unroll
    for (int i = 0; i < NBATCH; ++i) {
        int u  = tid + i * NTHREADS;
        int uc = (u < UNITS) ? u : 0;        // clamp tail to a safe in-bounds addr
        int k  = uc / CHUNKS4;
        int c  = uc - k * CHUNKS4;
        v[i] = *(const float4v*)(inb + (size_t)k * S_TOT + c * 4);
    }

    // ---------- Phase 1b: math + LDS transpose-scatter ----------
    #pragma unroll
    for (int i = 0; i < NBATCH; ++i) {
        int u = tid + i * NTHREADS;
        if (u >= UNITS) break;               // only trims the last batch slice
        int k  = u / CHUNKS4;
        int c  = u - k * CHUNKS4;
        int sl = c * 4;

        float r[4];
        if (k >= 4) {
            // conf + class scores: plain sigmoid (~95% of elements, convergent)
            #pragma unroll
            for (int j = 0; j < 4; ++j) r[j] = fast_sigmoid(v[i][j]);
        } else {
            // bx/by/bw/bh rows — only units u < 76 ever land here
            #pragma unroll
            for (int j = 0; j < 4; ++j) {
                float x  = v[i][j];
                int   sp = s0 + sl + j;       // global spatial index = h*76 + w
                int   hy = sp / WW_;
                int   wx = sp - hy * WW_;
                if      (k == 0) r[j] = ((float)wx + fast_sigmoid(x)) * (1.0f / 76.0f);
                else if (k == 1) r[j] = ((float)hy + fast_sigmoid(x)) * (1.0f / 76.0f);
                else if (k == 2) r[j] = __builtin_amdgcn_exp2f(x * LOG2E) * cw;
                else             r[j] = __builtin_amdgcn_exp2f(x * LOG2E) * ch;
            }
        }

        float* lp = &lds[sl * ATTR + k];
        #pragma unroll
        for (int j = 0; j < 4; ++j) lp[j * ATTR] = r[j];
    }

    __syncthreads();

    // ---------- Phase 2: contiguous LDS -> global, batched b128 reads + NT stores ----------
    // out tile base elem = (BA*5776 + s0)*85 ; (BA*5776 + s0) % 4 == 0 -> 16B aligned
    float4v* outv = (float4v*)(out + ((size_t)BA * S_TOT + s0) * ATTR);
    const float4v* ldsv = (const float4v*)lds;

    float4v w[NBATCH];
    #pragma unroll
    for (int i = 0; i < NBATCH; ++i) {
        int u  = tid + i * NTHREADS;
        int uc = (u < UNITS) ? u : 0;
        w[i] = ldsv[uc];
    }
    #pragma unroll
    for (int i = 0; i < NBATCH; ++i) {
        int u = tid + i * NTHREADS;
        if (u >= UNITS) break;
        __builtin_nontemporal_store(w[i], &outv[u]);  // write-once stream, keep L2 clean
    }
}

extern "C" void kernel_launch(void* const* d_in, const int* in_sizes, int n_in,
                              void* d_out, int out_size, void* d_ws, size_t ws_size,
                              hipStream_t stream) {
    const float* in = (const float*)d_in[0];   // fp32 input
    float* out = (float*)d_out;                // fp32 output

    dim3 grid(TILES, NB * NA);   // (76, 48) = 3648 blocks
    dim3 block(NTHREADS);
    yolo_layer_kernel<<<grid, block, 0, stream>>>(in, out);
}